// Round 1
// baseline (36771.469 us; speedup 1.0000x reference)
//
#include <hip/hip_runtime.h>
#include <hip/hip_cooperative_groups.h>
#include <cstddef>

#define EPSQ 1e-4f
#define S_TOT 512
#define BB 256
#define DH 256
#define NC 512

// ws offsets (in floats)
#define OFF_KIH 0
#define OFF_KHH 131072
#define OFF_KPH 262144
#define OFF_KPC 393216
#define OFF_BA  524288
#define OFF_BP  524800
#define OFF_H   525312
#define OFF_AC  590848
#define OFF_PH  721920
#define OFF_UPD 852992
#define OFF_X2  984064

union F4 { float4 v; float f[4]; };

// Hamilton-product component/sign tables: K[a*64+m][c*128+g] = sign[c][a]*w_{comp[c][a]}[m][g]
__constant__ int   d_comp[16] = {0,1,2,3, 1,0,3,2, 2,3,0,1, 3,2,1,0};
__constant__ float d_sign[16] = {1.f,-1.f,-1.f,-1.f, 1.f,1.f,-1.f,1.f, 1.f,1.f,1.f,-1.f, 1.f,-1.f,1.f,1.f};

__global__ void build_qk(const float* __restrict__ wr, const float* __restrict__ wi,
                         const float* __restrict__ wj, const float* __restrict__ wk,
                         float* __restrict__ K) {
  int idx = blockIdx.x * blockDim.x + threadIdx.x;
  if (idx >= 131072) return;
  int col = idx & 511, row = idx >> 9;
  int a = row >> 6, m = row & 63;
  int c = col >> 7, g = col & 127;
  int tt = c * 4 + a;
  int cc = d_comp[tt];
  const float* s = (cc == 0) ? wr : (cc == 1) ? wi : (cc == 2) ? wj : wk;
  K[idx] = d_sign[tt] * s[m * 128 + g];
}

__global__ void build_bias(const float* __restrict__ b1, const float* __restrict__ b2,
                           const float* __restrict__ b3, const float* __restrict__ b4,
                           float* __restrict__ bA, float* __restrict__ bP) {
  int i = blockIdx.x * blockDim.x + threadIdx.x;
  if (i < 512) { bA[i] = b1[i] + b2[i]; bP[i] = b3[i] + b4[i]; }
}

// X2[m][n] = sum_k A[m][k]*W[k][n] + bA[n];  A:[M][256], W:[256][512]
__global__ __launch_bounds__(256) void gemm_x2(
    const float* __restrict__ A, const float* __restrict__ W,
    const float* __restrict__ bA, float* __restrict__ C) {
  __shared__ float As[16][68];
  __shared__ float Ws[16][68];
  const int tid = threadIdx.x;
  const int nt = blockIdx.x, mt = blockIdx.y;
  const int m0 = mt * 64, n0 = nt * 64;
  const int tx = tid & 15, ty = tid >> 4;
  float acc[4][4];
#pragma unroll
  for (int i = 0; i < 4; i++)
#pragma unroll
    for (int j = 0; j < 4; j++) acc[i][j] = 0.f;
  const int lr = tid >> 2, lk = (tid & 3) * 4;
  const int wkr = tid >> 4, wn = (tid & 15) * 4;
  for (int k0 = 0; k0 < 256; k0 += 16) {
    float4 a4 = *(const float4*)(A + (size_t)(m0 + lr) * 256 + k0 + lk);
    float4 w4 = *(const float4*)(W + (size_t)(k0 + wkr) * 512 + n0 + wn);
    As[lk + 0][lr] = a4.x; As[lk + 1][lr] = a4.y; As[lk + 2][lr] = a4.z; As[lk + 3][lr] = a4.w;
    *(float4*)(&Ws[wkr][wn]) = w4;
    __syncthreads();
#pragma unroll
    for (int k = 0; k < 16; k++) {
      F4 av, wv;
      av.v = *(const float4*)(&As[k][ty * 4]);
      wv.v = *(const float4*)(&Ws[k][tx * 4]);
#pragma unroll
      for (int i = 0; i < 4; i++)
#pragma unroll
        for (int j = 0; j < 4; j++) acc[i][j] += av.f[i] * wv.f[j];
    }
    __syncthreads();
  }
  F4 b4; b4.v = *(const float4*)(bA + n0 + tx * 4);
#pragma unroll
  for (int i = 0; i < 4; i++) {
    int m = m0 + ty * 4 + i;
    F4 o;
#pragma unroll
    for (int j = 0; j < 4; j++) o.f[j] = acc[i][j] + b4.f[j];
    *(float4*)(C + (size_t)m * 512 + n0 + tx * 4) = o.v;
  }
}

// Persistent cooperative recurrent kernel. 256 blocks x 512 threads.
// bg = blk>>4 (16 batch rows each), cg = blk&15.
// Phase1: cols of [ac | ph] (1024): cg<8 -> ac slice (K_hh), cg>=8 -> ph slice (K_ph).
// Phase2: cand_t build (redundant per block) + upd slice (K_pc, 32 cols).
// Phase3: a_new + renormalize (redundant per block, hN stays in LDS).
__global__ __launch_bounds__(512, 2) void qru_seq(
    const float* __restrict__ X2,   // [steps][B][512]
    const float* __restrict__ h_in, // [B][256] raw h
    const float* __restrict__ Khh, const float* __restrict__ Kph,
    const float* __restrict__ Kpc, const float* __restrict__ bP,
    float* __restrict__ ac_g, float* __restrict__ ph_g, float* __restrict__ upd_g,
    float* __restrict__ h_out, float* __restrict__ out, float* __restrict__ hT,
    int steps) {
  cooperative_groups::grid_group gg = cooperative_groups::this_grid();
  __shared__ float Wmain[256][72];  // 72KB (pad 72 -> 2-way max on b32 col reads)
  __shared__ float Wpc[256][36];    // 36KB
  __shared__ float hNT[256][20];    // [k][r], normalized h, transposed
  __shared__ float candT[256][20];  // [k][r], cand_t, transposed

  const int tid = threadIdx.x;
  const int blk = blockIdx.x;
  const int bg = blk >> 4;
  const int cg = blk & 15;
  const int row0 = bg * 16;

  // ---- persistent weight slices -> LDS ----
  {
    const float* src = (cg < 8) ? (Khh + cg * 64) : (Kph + (cg - 8) * 64);
    for (int i = tid; i < 4096; i += 512) {   // 256 rows x 16 quads
      int r = i >> 4, c4 = (i & 15) * 4;
      float4 v = *(const float4*)(src + (size_t)r * 512 + c4);
      Wmain[r][c4 + 0] = v.x; Wmain[r][c4 + 1] = v.y; Wmain[r][c4 + 2] = v.z; Wmain[r][c4 + 3] = v.w;
    }
    const float* srcp = Kpc + cg * 32;
    for (int i = tid; i < 2048; i += 512) {   // 256 rows x 8 quads
      int r = i >> 3, c4 = (i & 7) * 4;
      float4 v = *(const float4*)(srcp + (size_t)r * 512 + c4);
      Wpc[r][c4 + 0] = v.x; Wpc[r][c4 + 1] = v.y; Wpc[r][c4 + 2] = v.z; Wpc[r][c4 + 3] = v.w;
    }
  }
  // ---- init hNT = normalize(h_in) ----
  if (tid < 256) {
    int r = tid >> 4, q4 = (tid & 15) * 4;
    F4 v[4];
#pragma unroll
    for (int a = 0; a < 4; a++)
      v[a].v = *(const float4*)(h_in + (size_t)(row0 + r) * 256 + a * 64 + q4);
#pragma unroll
    for (int j = 0; j < 4; j++) {
      float ss = v[0].f[j] * v[0].f[j] + v[1].f[j] * v[1].f[j] + v[2].f[j] * v[2].f[j] + v[3].f[j] * v[3].f[j];
      float inv = 1.f / (sqrtf(ss) + EPSQ);
#pragma unroll
      for (int a = 0; a < 4; a++) hNT[a * 64 + q4 + j][r] = v[a].f[j] * inv;
    }
  }
  __syncthreads();

  const int wave = tid >> 6;
  const int lane = tid & 63;

  for (int t = 0; t < steps; ++t) {
    // ================= PHASE 1: ac/ph slices =================
    {
      const int tile = lane & 7;
      const int cq = tile & 1;
      const int rq = (tile >> 1) & 3;
      const int ks = lane >> 3;            // 8-way k split, in-wave
      const int col0 = wave * 8 + cq * 4;  // local col quad base (0..60)
      float acc[4][4];
#pragma unroll
      for (int i = 0; i < 4; i++)
#pragma unroll
        for (int j = 0; j < 4; j++) acc[i][j] = 0.f;
#pragma unroll 8
      for (int i = 0; i < 32; i++) {
        const int k = ks + 8 * i;
        F4 w4, h4;
        w4.v = *(const float4*)(&Wmain[k][col0]);
        h4.v = *(const float4*)(&hNT[k][rq * 4]);
#pragma unroll
        for (int ii = 0; ii < 4; ii++)
#pragma unroll
          for (int jj = 0; jj < 4; jj++) acc[ii][jj] += h4.f[ii] * w4.f[jj];
      }
      // select-exchange reduction over ks bits (lane bits 3,4,5)
      const int b0 = ks & 1, b1 = (ks >> 1) & 1, b2 = ks >> 2;
      float r8[2][4];
#pragma unroll
      for (int i2 = 0; i2 < 2; i2++)
#pragma unroll
        for (int jj = 0; jj < 4; jj++) {
          float keep = b0 ? acc[2 * i2 + 1][jj] : acc[2 * i2][jj];
          float give = b0 ? acc[2 * i2][jj] : acc[2 * i2 + 1][jj];
          r8[i2][jj] = keep + __shfl_xor(give, 8);
        }
      float r4[4];
#pragma unroll
      for (int jj = 0; jj < 4; jj++) {
        float keep = b1 ? r8[1][jj] : r8[0][jj];
        float give = b1 ? r8[0][jj] : r8[1][jj];
        r4[jj] = keep + __shfl_xor(give, 16);
      }
      float r2[2];
#pragma unroll
      for (int j2 = 0; j2 < 2; j2++) {
        float keep = b2 ? r4[2 + j2] : r4[j2];
        float give = b2 ? r4[j2] : r4[2 + j2];
        r2[j2] = keep + __shfl_xor(give, 32);
      }
      const int ii = ks & 3;
      const int row = row0 + rq * 4 + ii;
      if (cg < 8) {
        const int colA = cg * 64 + col0 + 2 * b2;
        size_t xo = ((size_t)t * BB + row) * 512 + colA;
        ac_g[(size_t)row * 512 + colA]     = r2[0] + X2[xo];
        ac_g[(size_t)row * 512 + colA + 1] = r2[1] + X2[xo + 1];
      } else {
        const int colP = (cg - 8) * 64 + col0 + 2 * b2;
        ph_g[(size_t)row * 512 + colP]     = r2[0] + bP[colP];
        ph_g[(size_t)row * 512 + colP + 1] = r2[1] + bP[colP + 1];
      }
    }
    gg.sync();
    // ================= PHASE 2: cand_t + upd slice =================
    if (tid < 256) {  // build candT for this bg (redundant per block)
      int r = tid >> 4, q4 = (tid & 15) * 4;
      F4 am[4], cn[4];
#pragma unroll
      for (int a = 0; a < 4; a++) {
        am[a].v = *(const float4*)(ac_g + (size_t)(row0 + r) * 512 + a * 128 + q4);
        cn[a].v = *(const float4*)(ac_g + (size_t)(row0 + r) * 512 + a * 128 + 64 + q4);
      }
#pragma unroll
      for (int j = 0; j < 4; j++) {
        float ag = sqrtf(am[0].f[j] * am[0].f[j] + am[1].f[j] * am[1].f[j] +
                         am[2].f[j] * am[2].f[j] + am[3].f[j] * am[3].f[j]);
        float t0 = cn[0].f[j] * ag, t1 = cn[1].f[j] * ag, t2 = cn[2].f[j] * ag, t3 = cn[3].f[j] * ag;
        float mc = sqrtf(t0 * t0 + t1 * t1 + t2 * t2 + t3 * t3);
        float inv = 1.f / (mc + EPSQ);
        candT[0 * 64 + q4 + j][r] = t0 * inv;
        candT[1 * 64 + q4 + j][r] = t1 * inv;
        candT[2 * 64 + q4 + j][r] = t2 * inv;
        candT[3 * 64 + q4 + j][r] = t3 * inv;
      }
    }
    __syncthreads();
    {
      const int rq = lane & 3;
      const int ks = lane >> 2;            // 16-way k split, in-wave
      float acc[4][4];
#pragma unroll
      for (int i = 0; i < 4; i++)
#pragma unroll
        for (int j = 0; j < 4; j++) acc[i][j] = 0.f;
#pragma unroll 8
      for (int i = 0; i < 16; i++) {
        const int k = ks + 16 * i;
        F4 w4, c4;
        w4.v = *(const float4*)(&Wpc[k][wave * 4]);
        c4.v = *(const float4*)(&candT[k][rq * 4]);
#pragma unroll
        for (int ii = 0; ii < 4; ii++)
#pragma unroll
          for (int jj = 0; jj < 4; jj++) acc[ii][jj] += c4.f[ii] * w4.f[jj];
      }
      const int b0 = ks & 1, b1 = (ks >> 1) & 1, b2 = (ks >> 2) & 1, b3 = ks >> 3;
      float r8[2][4];
#pragma unroll
      for (int i2 = 0; i2 < 2; i2++)
#pragma unroll
        for (int jj = 0; jj < 4; jj++) {
          float keep = b0 ? acc[2 * i2 + 1][jj] : acc[2 * i2][jj];
          float give = b0 ? acc[2 * i2][jj] : acc[2 * i2 + 1][jj];
          r8[i2][jj] = keep + __shfl_xor(give, 4);
        }
      float r4[4];
#pragma unroll
      for (int jj = 0; jj < 4; jj++) {
        float keep = b1 ? r8[1][jj] : r8[0][jj];
        float give = b1 ? r8[0][jj] : r8[1][jj];
        r4[jj] = keep + __shfl_xor(give, 8);
      }
      float rr[2];
#pragma unroll
      for (int m = 0; m < 2; m++) {
        float keep = b2 ? r4[2 * m + 1] : r4[2 * m];
        float give = b2 ? r4[2 * m] : r4[2 * m + 1];
        rr[m] = keep + __shfl_xor(give, 16);
      }
      float vfin;
      {
        float keep = b3 ? rr[1] : rr[0];
        float give = b3 ? rr[0] : rr[1];
        vfin = keep + __shfl_xor(give, 32);
      }
      const int ii = ks & 3, jj = ks >> 2;
      const int row = row0 + rq * 4 + ii;
      const int colP = cg * 32 + wave * 4 + jj;
      vfin += ph_g[(size_t)row * 512 + colP];
      upd_g[(size_t)row * 512 + colP] = vfin;
    }
    gg.sync();
    // ================= PHASE 3: a_new, output, renormalize =================
    if (tid < 256) {
      int r = tid >> 4, q4 = (tid & 15) * 4;
      const float* ur = upd_g + (size_t)(row0 + r) * 512;
      F4 u0, u1, u2, u3, u4, u5, u7;
      u0.v = *(const float4*)(ur + 0 * 64 + q4);
      u1.v = *(const float4*)(ur + 1 * 64 + q4);
      u2.v = *(const float4*)(ur + 2 * 64 + q4);
      u3.v = *(const float4*)(ur + 3 * 64 + q4);
      u4.v = *(const float4*)(ur + 4 * 64 + q4);
      u5.v = *(const float4*)(ur + 5 * 64 + q4);
      u7.v = *(const float4*)(ur + 7 * 64 + q4);
      F4 anew[4]; float invm[4];
#pragma unroll
      for (int j = 0; j < 4; j++) {
        float mh = sqrtf(u0.f[j] * u0.f[j] + 2.f * u2.f[j] * u2.f[j] + u4.f[j] * u4.f[j]);
        float mc = sqrtf(u1.f[j] * u1.f[j] + u3.f[j] * u3.f[j] + u5.f[j] * u5.f[j] + u7.f[j] * u7.f[j]);
        float s = 0.f;
#pragma unroll
        for (int a = 0; a < 4; a++) {
          float av = hNT[a * 64 + q4 + j][r] * mh + candT[a * 64 + q4 + j][r] * mc;
          anew[a].f[j] = av;
          s += av * av;
        }
        invm[j] = 1.f / (sqrtf(s) + EPSQ);
      }
      if (cg == 0) {
#pragma unroll
        for (int a = 0; a < 4; a++)
          *(float4*)(out + ((size_t)t * BB + row0 + r) * 256 + a * 64 + q4) = anew[a].v;
        if (t == steps - 1) {
#pragma unroll
          for (int a = 0; a < 4; a++)
            *(float4*)(h_out + (size_t)(row0 + r) * 256 + a * 64 + q4) = anew[a].v;
          if (hT != nullptr) {
#pragma unroll
            for (int a = 0; a < 4; a++)
              *(float4*)(hT + (size_t)(row0 + r) * 256 + a * 64 + q4) = anew[a].v;
          }
        }
      }
#pragma unroll
      for (int j = 0; j < 4; j++)
#pragma unroll
        for (int a = 0; a < 4; a++)
          hNT[a * 64 + q4 + j][r] = anew[a].f[j] * invm[j];
    }
    __syncthreads();
  }
}

extern "C" void kernel_launch(void* const* d_in, const int* in_sizes, int n_in,
                              void* d_out, int out_size, void* d_ws, size_t ws_size,
                              hipStream_t stream) {
  const float* input = (const float*)d_in[0];
  const float* hx = (const float*)d_in[1];
  float* ws = (float*)d_ws;
  float* Kih = ws + OFF_KIH;
  float* Khh = ws + OFF_KHH;
  float* Kph = ws + OFF_KPH;
  float* Kpc = ws + OFF_KPC;
  float* bA = ws + OFF_BA;
  float* bP = ws + OFF_BP;
  float* Hst = ws + OFF_H;
  float* acb = ws + OFF_AC;
  float* phb = ws + OFF_PH;
  float* updb = ws + OFF_UPD;
  float* X2b = ws + OFF_X2;

  build_qk<<<512, 256, 0, stream>>>((const float*)d_in[2], (const float*)d_in[3],
                                    (const float*)d_in[4], (const float*)d_in[5], Kih);
  build_qk<<<512, 256, 0, stream>>>((const float*)d_in[6], (const float*)d_in[7],
                                    (const float*)d_in[8], (const float*)d_in[9], Khh);
  build_qk<<<512, 256, 0, stream>>>((const float*)d_in[10], (const float*)d_in[11],
                                    (const float*)d_in[12], (const float*)d_in[13], Kpc);
  build_qk<<<512, 256, 0, stream>>>((const float*)d_in[14], (const float*)d_in[15],
                                    (const float*)d_in[16], (const float*)d_in[17], Kph);
  build_bias<<<2, 256, 0, stream>>>((const float*)d_in[18], (const float*)d_in[19],
                                    (const float*)d_in[20], (const float*)d_in[21], bA, bP);

  // pick largest chunk of steps whose X2 buffer fits in ws
  int CHv = 64;
  while (CHv > 8 && ((size_t)OFF_X2 + (size_t)CHv * BB * NC) * 4 > ws_size) CHv >>= 1;
  const int nch = S_TOT / CHv;

  for (int c = 0; c < nch; ++c) {
    gemm_x2<<<dim3(8, CHv * 4), 256, 0, stream>>>(
        input + (size_t)c * CHv * BB * DH, Kih, bA, X2b);

    const float* X2p = X2b;
    const float* hsrc = (c == 0) ? hx : (const float*)Hst;
    const float* Khhp = Khh; const float* Kphp = Kph; const float* Kpcp = Kpc;
    const float* bPp = bP;
    float* acp = acb; float* php = phb; float* updp = updb; float* hop = Hst;
    float* outp = (float*)d_out + (size_t)c * CHv * BB * DH;
    float* hTp = (c == nch - 1) ? ((float*)d_out + (size_t)S_TOT * BB * DH) : nullptr;
    int steps = CHv;
    void* args[13];
    args[0] = (void*)&X2p;  args[1] = (void*)&hsrc; args[2] = (void*)&Khhp;
    args[3] = (void*)&Kphp; args[4] = (void*)&Kpcp; args[5] = (void*)&bPp;
    args[6] = (void*)&acp;  args[7] = (void*)&php;  args[8] = (void*)&updp;
    args[9] = (void*)&hop;  args[10] = (void*)&outp; args[11] = (void*)&hTp;
    args[12] = (void*)&steps;
    hipLaunchCooperativeKernel((const void*)qru_seq, dim3(256), dim3(512), args, 0, stream);
  }
}

// Round 2
// 15762.941 us; speedup vs baseline: 2.3328x; 2.3328x over previous
//
#include <hip/hip_runtime.h>
#include <cstddef>

#define EPSQ 1e-4f
#define S_TOT 512
#define BB 256
#define DH 256
#define NC 512

// ws offsets (in floats)
#define OFF_KIH 0
#define OFF_KHH 131072
#define OFF_KPH 262144
#define OFF_KPC 393216
#define OFF_BA  524288
#define OFF_BP  524800
#define OFF_H   525312
#define OFF_AC  590848
#define OFF_PH  721920
#define OFF_UPD 852992
#define OFF_CTR 984064
#define OFF_X2  984384

union F4 { float4 v; float f[4]; };

// Hamilton-product component/sign tables: K[a*64+m][c*128+g] = sign[c][a]*w_{comp[c][a]}[m][g]
__constant__ int   d_comp[16] = {0,1,2,3, 1,0,3,2, 2,3,0,1, 3,2,1,0};
__constant__ float d_sign[16] = {1.f,-1.f,-1.f,-1.f, 1.f,1.f,-1.f,1.f, 1.f,1.f,1.f,-1.f, 1.f,-1.f,1.f,1.f};

__global__ void build_qk(const float* __restrict__ wr, const float* __restrict__ wi,
                         const float* __restrict__ wj, const float* __restrict__ wk,
                         float* __restrict__ K) {
  int idx = blockIdx.x * blockDim.x + threadIdx.x;
  if (idx >= 131072) return;
  int col = idx & 511, row = idx >> 9;
  int a = row >> 6, m = row & 63;
  int c = col >> 7, g = col & 127;
  int tt = c * 4 + a;
  int cc = d_comp[tt];
  const float* s = (cc == 0) ? wr : (cc == 1) ? wi : (cc == 2) ? wj : wk;
  K[idx] = d_sign[tt] * s[m * 128 + g];
}

__global__ void build_bias(const float* __restrict__ b1, const float* __restrict__ b2,
                           const float* __restrict__ b3, const float* __restrict__ b4,
                           float* __restrict__ bA, float* __restrict__ bP) {
  int i = blockIdx.x * blockDim.x + threadIdx.x;
  if (i < 512) { bA[i] = b1[i] + b2[i]; bP[i] = b3[i] + b4[i]; }
}

__global__ void zero_ctr(int* ctr) {
  if (threadIdx.x < 256) ctr[threadIdx.x] = 0;
}

// X2[m][n] = sum_k A[m][k]*W[k][n] + bA[n];  A:[M][256], W:[256][512]
__global__ __launch_bounds__(256) void gemm_x2(
    const float* __restrict__ A, const float* __restrict__ W,
    const float* __restrict__ bA, float* __restrict__ C) {
  __shared__ float As[16][68];
  __shared__ float Ws[16][68];
  const int tid = threadIdx.x;
  const int nt = blockIdx.x, mt = blockIdx.y;
  const int m0 = mt * 64, n0 = nt * 64;
  const int tx = tid & 15, ty = tid >> 4;
  float acc[4][4];
#pragma unroll
  for (int i = 0; i < 4; i++)
#pragma unroll
    for (int j = 0; j < 4; j++) acc[i][j] = 0.f;
  const int lr = tid >> 2, lk = (tid & 3) * 4;
  const int wkr = tid >> 4, wn = (tid & 15) * 4;
  for (int k0 = 0; k0 < 256; k0 += 16) {
    float4 a4 = *(const float4*)(A + (size_t)(m0 + lr) * 256 + k0 + lk);
    float4 w4 = *(const float4*)(W + (size_t)(k0 + wkr) * 512 + n0 + wn);
    As[lk + 0][lr] = a4.x; As[lk + 1][lr] = a4.y; As[lk + 2][lr] = a4.z; As[lk + 3][lr] = a4.w;
    *(float4*)(&Ws[wkr][wn]) = w4;
    __syncthreads();
#pragma unroll
    for (int k = 0; k < 16; k++) {
      F4 av, wv;
      av.v = *(const float4*)(&As[k][ty * 4]);
      wv.v = *(const float4*)(&Ws[k][tx * 4]);
#pragma unroll
      for (int i = 0; i < 4; i++)
#pragma unroll
        for (int j = 0; j < 4; j++) acc[i][j] += av.f[i] * wv.f[j];
    }
    __syncthreads();
  }
  F4 b4; b4.v = *(const float4*)(bA + n0 + tx * 4);
#pragma unroll
  for (int i = 0; i < 4; i++) {
    int m = m0 + ty * 4 + i;
    F4 o;
#pragma unroll
    for (int j = 0; j < 4; j++) o.f[j] = acc[i][j] + b4.f[j];
    *(float4*)(C + (size_t)m * 512 + n0 + tx * 4) = o.v;
  }
}

// Per-cluster barrier: 16 blocks arrive at a monotonically-increasing counter.
// Release: __syncthreads drained vmcnt + __threadfence (agent acq_rel ->
// buffer_wbl2/inv sc1 on gfx950). Acquire: spin + trailing __threadfence.
__device__ __forceinline__ void cl_barrier(int* ctr, int target) {
  __syncthreads();
  if (threadIdx.x == 0) {
    __threadfence();
    __hip_atomic_fetch_add(ctr, 1, __ATOMIC_RELAXED, __HIP_MEMORY_SCOPE_AGENT);
    while (__hip_atomic_load(ctr, __ATOMIC_RELAXED, __HIP_MEMORY_SCOPE_AGENT) < target) {
    }
    __threadfence();
  }
  __syncthreads();
}

// Persistent recurrent kernel. 256 blocks x 512 threads, 1 block/CU.
// Cluster swizzle: bg = blk&15 (16 batch rows each), cg = blk>>4 —
// a cluster's 16 blocks share blk%8, i.e. one XCD under round-robin mapping.
// Phase1: cols of [ac | ph]: cg<8 -> ac slice (K_hh), cg>=8 -> ph slice (K_ph).
// Phase2: cand_t build (redundant per block) + upd slice (K_pc, 32 cols).
// Phase3: a_new + renormalize (redundant per block, hN stays in LDS).
__global__ __launch_bounds__(512, 2) void qru_seq(
    const float* __restrict__ X2,   // [steps][B][512]
    const float* __restrict__ h_in, // [B][256] raw h
    const float* __restrict__ Khh, const float* __restrict__ Kph,
    const float* __restrict__ Kpc, const float* __restrict__ bP,
    float* __restrict__ ac_g, float* __restrict__ ph_g, float* __restrict__ upd_g,
    float* __restrict__ h_out, float* __restrict__ out, float* __restrict__ hT,
    int* __restrict__ ctr_base, int t0, int steps) {
  __shared__ float Wmain[256][72];  // 72KB
  __shared__ float Wpc[256][36];    // 36KB
  __shared__ float hNT[256][20];    // [k][r], normalized h, transposed
  __shared__ float candT[256][20];  // [k][r], cand_t, transposed

  const int tid = threadIdx.x;
  const int blk = blockIdx.x;
  const int bg = blk & 15;
  const int cg = blk >> 4;
  const int row0 = bg * 16;
  int* ctr = ctr_base + bg * 16;    // 64B-padded counter per cluster

  // ---- persistent weight slices -> LDS ----
  {
    const float* src = (cg < 8) ? (Khh + cg * 64) : (Kph + (cg - 8) * 64);
    for (int i = tid; i < 4096; i += 512) {   // 256 rows x 16 quads
      int r = i >> 4, c4 = (i & 15) * 4;
      float4 v = *(const float4*)(src + (size_t)r * 512 + c4);
      Wmain[r][c4 + 0] = v.x; Wmain[r][c4 + 1] = v.y; Wmain[r][c4 + 2] = v.z; Wmain[r][c4 + 3] = v.w;
    }
    const float* srcp = Kpc + cg * 32;
    for (int i = tid; i < 2048; i += 512) {   // 256 rows x 8 quads
      int r = i >> 3, c4 = (i & 7) * 4;
      float4 v = *(const float4*)(srcp + (size_t)r * 512 + c4);
      Wpc[r][c4 + 0] = v.x; Wpc[r][c4 + 1] = v.y; Wpc[r][c4 + 2] = v.z; Wpc[r][c4 + 3] = v.w;
    }
  }
  // ---- init hNT = normalize(h_in) ----
  if (tid < 256) {
    int r = tid >> 4, q4 = (tid & 15) * 4;
    F4 v[4];
#pragma unroll
    for (int a = 0; a < 4; a++)
      v[a].v = *(const float4*)(h_in + (size_t)(row0 + r) * 256 + a * 64 + q4);
#pragma unroll
    for (int j = 0; j < 4; j++) {
      float ss = v[0].f[j] * v[0].f[j] + v[1].f[j] * v[1].f[j] + v[2].f[j] * v[2].f[j] + v[3].f[j] * v[3].f[j];
      float inv = 1.f / (sqrtf(ss) + EPSQ);
#pragma unroll
      for (int a = 0; a < 4; a++) hNT[a * 64 + q4 + j][r] = v[a].f[j] * inv;
    }
  }
  __syncthreads();

  const int wave = tid >> 6;
  const int lane = tid & 63;

  for (int t = 0; t < steps; ++t) {
    const int g = t0 + t;
    // ================= PHASE 1: ac/ph slices =================
    {
      const int tile = lane & 7;
      const int cq = tile & 1;
      const int rq = (tile >> 1) & 3;
      const int ks = lane >> 3;            // 8-way k split, in-wave
      const int col0 = wave * 8 + cq * 4;  // local col quad base (0..60)
      float acc[4][4];
#pragma unroll
      for (int i = 0; i < 4; i++)
#pragma unroll
        for (int j = 0; j < 4; j++) acc[i][j] = 0.f;
#pragma unroll 8
      for (int i = 0; i < 32; i++) {
        const int k = ks + 8 * i;
        F4 w4, h4;
        w4.v = *(const float4*)(&Wmain[k][col0]);
        h4.v = *(const float4*)(&hNT[k][rq * 4]);
#pragma unroll
        for (int ii = 0; ii < 4; ii++)
#pragma unroll
          for (int jj = 0; jj < 4; jj++) acc[ii][jj] += h4.f[ii] * w4.f[jj];
      }
      // select-exchange reduction over ks bits (lane bits 3,4,5)
      const int b0 = ks & 1, b1 = (ks >> 1) & 1, b2 = ks >> 2;
      float r8[2][4];
#pragma unroll
      for (int i2 = 0; i2 < 2; i2++)
#pragma unroll
        for (int jj = 0; jj < 4; jj++) {
          float keep = b0 ? acc[2 * i2 + 1][jj] : acc[2 * i2][jj];
          float give = b0 ? acc[2 * i2][jj] : acc[2 * i2 + 1][jj];
          r8[i2][jj] = keep + __shfl_xor(give, 8);
        }
      float r4[4];
#pragma unroll
      for (int jj = 0; jj < 4; jj++) {
        float keep = b1 ? r8[1][jj] : r8[0][jj];
        float give = b1 ? r8[0][jj] : r8[1][jj];
        r4[jj] = keep + __shfl_xor(give, 16);
      }
      float r2[2];
#pragma unroll
      for (int j2 = 0; j2 < 2; j2++) {
        float keep = b2 ? r4[2 + j2] : r4[j2];
        float give = b2 ? r4[j2] : r4[2 + j2];
        r2[j2] = keep + __shfl_xor(give, 32);
      }
      const int ii = ks & 3;
      const int row = row0 + rq * 4 + ii;
      if (cg < 8) {
        const int colA = cg * 64 + col0 + 2 * b2;
        size_t xo = ((size_t)t * BB + row) * 512 + colA;
        ac_g[(size_t)row * 512 + colA]     = r2[0] + X2[xo];
        ac_g[(size_t)row * 512 + colA + 1] = r2[1] + X2[xo + 1];
      } else {
        const int colP = (cg - 8) * 64 + col0 + 2 * b2;
        ph_g[(size_t)row * 512 + colP]     = r2[0] + bP[colP];
        ph_g[(size_t)row * 512 + colP + 1] = r2[1] + bP[colP + 1];
      }
    }
    cl_barrier(ctr, (2 * g + 1) * 16);
    // ================= PHASE 2: cand_t + upd slice =================
    if (tid < 256) {  // build candT for this bg (redundant per block)
      int r = tid >> 4, q4 = (tid & 15) * 4;
      F4 am[4], cn[4];
#pragma unroll
      for (int a = 0; a < 4; a++) {
        am[a].v = *(const float4*)(ac_g + (size_t)(row0 + r) * 512 + a * 128 + q4);
        cn[a].v = *(const float4*)(ac_g + (size_t)(row0 + r) * 512 + a * 128 + 64 + q4);
      }
#pragma unroll
      for (int j = 0; j < 4; j++) {
        float ag = sqrtf(am[0].f[j] * am[0].f[j] + am[1].f[j] * am[1].f[j] +
                         am[2].f[j] * am[2].f[j] + am[3].f[j] * am[3].f[j]);
        float t0v = cn[0].f[j] * ag, t1 = cn[1].f[j] * ag, t2 = cn[2].f[j] * ag, t3 = cn[3].f[j] * ag;
        float mc = sqrtf(t0v * t0v + t1 * t1 + t2 * t2 + t3 * t3);
        float inv = 1.f / (mc + EPSQ);
        candT[0 * 64 + q4 + j][r] = t0v * inv;
        candT[1 * 64 + q4 + j][r] = t1 * inv;
        candT[2 * 64 + q4 + j][r] = t2 * inv;
        candT[3 * 64 + q4 + j][r] = t3 * inv;
      }
    }
    __syncthreads();
    {
      const int rq = lane & 3;
      const int ks = lane >> 2;            // 16-way k split, in-wave
      float acc[4][4];
#pragma unroll
      for (int i = 0; i < 4; i++)
#pragma unroll
        for (int j = 0; j < 4; j++) acc[i][j] = 0.f;
#pragma unroll 8
      for (int i = 0; i < 16; i++) {
        const int k = ks + 16 * i;
        F4 w4, c4;
        w4.v = *(const float4*)(&Wpc[k][wave * 4]);
        c4.v = *(const float4*)(&candT[k][rq * 4]);
#pragma unroll
        for (int ii = 0; ii < 4; ii++)
#pragma unroll
          for (int jj = 0; jj < 4; jj++) acc[ii][jj] += c4.f[ii] * w4.f[jj];
      }
      const int b0 = ks & 1, b1 = (ks >> 1) & 1, b2 = (ks >> 2) & 1, b3 = ks >> 3;
      float r8[2][4];
#pragma unroll
      for (int i2 = 0; i2 < 2; i2++)
#pragma unroll
        for (int jj = 0; jj < 4; jj++) {
          float keep = b0 ? acc[2 * i2 + 1][jj] : acc[2 * i2][jj];
          float give = b0 ? acc[2 * i2][jj] : acc[2 * i2 + 1][jj];
          r8[i2][jj] = keep + __shfl_xor(give, 4);
        }
      float r4[4];
#pragma unroll
      for (int jj = 0; jj < 4; jj++) {
        float keep = b1 ? r8[1][jj] : r8[0][jj];
        float give = b1 ? r8[0][jj] : r8[1][jj];
        r4[jj] = keep + __shfl_xor(give, 8);
      }
      float rr[2];
#pragma unroll
      for (int m = 0; m < 2; m++) {
        float keep = b2 ? r4[2 * m + 1] : r4[2 * m];
        float give = b2 ? r4[2 * m] : r4[2 * m + 1];
        rr[m] = keep + __shfl_xor(give, 16);
      }
      float vfin;
      {
        float keep = b3 ? rr[1] : rr[0];
        float give = b3 ? rr[0] : rr[1];
        vfin = keep + __shfl_xor(give, 32);
      }
      const int ii = ks & 3, jj = ks >> 2;
      const int row = row0 + rq * 4 + ii;
      const int colP = cg * 32 + wave * 4 + jj;
      vfin += ph_g[(size_t)row * 512 + colP];
      upd_g[(size_t)row * 512 + colP] = vfin;
    }
    cl_barrier(ctr, (2 * g + 2) * 16);
    // ================= PHASE 3: a_new, output, renormalize =================
    if (tid < 256) {
      int r = tid >> 4, q4 = (tid & 15) * 4;
      const float* ur = upd_g + (size_t)(row0 + r) * 512;
      F4 u0, u1, u2, u3, u4, u5, u7;
      u0.v = *(const float4*)(ur + 0 * 64 + q4);
      u1.v = *(const float4*)(ur + 1 * 64 + q4);
      u2.v = *(const float4*)(ur + 2 * 64 + q4);
      u3.v = *(const float4*)(ur + 3 * 64 + q4);
      u4.v = *(const float4*)(ur + 4 * 64 + q4);
      u5.v = *(const float4*)(ur + 5 * 64 + q4);
      u7.v = *(const float4*)(ur + 7 * 64 + q4);
      F4 anew[4]; float invm[4];
#pragma unroll
      for (int j = 0; j < 4; j++) {
        float mh = sqrtf(u0.f[j] * u0.f[j] + 2.f * u2.f[j] * u2.f[j] + u4.f[j] * u4.f[j]);
        float mc = sqrtf(u1.f[j] * u1.f[j] + u3.f[j] * u3.f[j] + u5.f[j] * u5.f[j] + u7.f[j] * u7.f[j]);
        float s = 0.f;
#pragma unroll
        for (int a = 0; a < 4; a++) {
          float av = hNT[a * 64 + q4 + j][r] * mh + candT[a * 64 + q4 + j][r] * mc;
          anew[a].f[j] = av;
          s += av * av;
        }
        invm[j] = 1.f / (sqrtf(s) + EPSQ);
      }
      if (cg == 0) {
#pragma unroll
        for (int a = 0; a < 4; a++)
          *(float4*)(out + ((size_t)t * BB + row0 + r) * 256 + a * 64 + q4) = anew[a].v;
        if (t == steps - 1) {
#pragma unroll
          for (int a = 0; a < 4; a++)
            *(float4*)(h_out + (size_t)(row0 + r) * 256 + a * 64 + q4) = anew[a].v;
          if (hT != nullptr) {
#pragma unroll
            for (int a = 0; a < 4; a++)
              *(float4*)(hT + (size_t)(row0 + r) * 256 + a * 64 + q4) = anew[a].v;
          }
        }
      }
#pragma unroll
      for (int j = 0; j < 4; j++)
#pragma unroll
        for (int a = 0; a < 4; a++)
          hNT[a * 64 + q4 + j][r] = anew[a].f[j] * invm[j];
    }
    __syncthreads();
  }
}

extern "C" void kernel_launch(void* const* d_in, const int* in_sizes, int n_in,
                              void* d_out, int out_size, void* d_ws, size_t ws_size,
                              hipStream_t stream) {
  const float* input = (const float*)d_in[0];
  const float* hx = (const float*)d_in[1];
  float* ws = (float*)d_ws;
  float* Kih = ws + OFF_KIH;
  float* Khh = ws + OFF_KHH;
  float* Kph = ws + OFF_KPH;
  float* Kpc = ws + OFF_KPC;
  float* bA = ws + OFF_BA;
  float* bP = ws + OFF_BP;
  float* Hst = ws + OFF_H;
  float* acb = ws + OFF_AC;
  float* phb = ws + OFF_PH;
  float* updb = ws + OFF_UPD;
  int*   ctrb = (int*)(ws + OFF_CTR);
  float* X2b = ws + OFF_X2;

  build_qk<<<512, 256, 0, stream>>>((const float*)d_in[2], (const float*)d_in[3],
                                    (const float*)d_in[4], (const float*)d_in[5], Kih);
  build_qk<<<512, 256, 0, stream>>>((const float*)d_in[6], (const float*)d_in[7],
                                    (const float*)d_in[8], (const float*)d_in[9], Khh);
  build_qk<<<512, 256, 0, stream>>>((const float*)d_in[10], (const float*)d_in[11],
                                    (const float*)d_in[12], (const float*)d_in[13], Kpc);
  build_qk<<<512, 256, 0, stream>>>((const float*)d_in[14], (const float*)d_in[15],
                                    (const float*)d_in[16], (const float*)d_in[17], Kph);
  build_bias<<<2, 256, 0, stream>>>((const float*)d_in[18], (const float*)d_in[19],
                                    (const float*)d_in[20], (const float*)d_in[21], bA, bP);
  zero_ctr<<<1, 256, 0, stream>>>(ctrb);

  // pick largest chunk of steps whose X2 buffer fits in ws
  int CHv = 64;
  while (CHv > 8 && ((size_t)OFF_X2 + (size_t)CHv * BB * NC) * 4 > ws_size) CHv >>= 1;
  const int nch = S_TOT / CHv;

  for (int c = 0; c < nch; ++c) {
    gemm_x2<<<dim3(8, CHv * 4), 256, 0, stream>>>(
        input + (size_t)c * CHv * BB * DH, Kih, bA, X2b);

    const float* X2p = X2b;
    const float* hsrc = (c == 0) ? hx : (const float*)Hst;
    const float* Khhp = Khh; const float* Kphp = Kph; const float* Kpcp = Kpc;
    const float* bPp = bP;
    float* acp = acb; float* php = phb; float* updp = updb; float* hop = Hst;
    float* outp = (float*)d_out + (size_t)c * CHv * BB * DH;
    float* hTp = (c == nch - 1) ? ((float*)d_out + (size_t)S_TOT * BB * DH) : nullptr;
    int t0 = c * CHv;
    int steps = CHv;
    void* args[15];
    args[0] = (void*)&X2p;  args[1] = (void*)&hsrc; args[2] = (void*)&Khhp;
    args[3] = (void*)&Kphp; args[4] = (void*)&Kpcp; args[5] = (void*)&bPp;
    args[6] = (void*)&acp;  args[7] = (void*)&php;  args[8] = (void*)&updp;
    args[9] = (void*)&hop;  args[10] = (void*)&outp; args[11] = (void*)&hTp;
    args[12] = (void*)&ctrb; args[13] = (void*)&t0; args[14] = (void*)&steps;
    hipLaunchCooperativeKernel((const void*)qru_seq, dim3(256), dim3(512), args, 0, stream);
  }
}